// Round 1
// 337.758 us; speedup vs baseline: 1.0656x; 1.0656x over previous
//
#include <hip/hip_runtime.h>

#define NEG_SLOPE 0.2f
#define SCAN_B 1024

typedef __attribute__((ext_vector_type(8))) short bf16x8;   // MFMA A/B frag
typedef __attribute__((ext_vector_type(4))) float f32x4;    // MFMA C/D frag

// fp32 -> bf16 round-to-nearest-even (no NaN inputs here).
__device__ __forceinline__ unsigned short f2b(float f) {
    unsigned int u = __float_as_uint(f);
    u += 0x7FFFu + ((u >> 16) & 1u);
    return (unsigned short)(u >> 16);
}
__device__ __forceinline__ float blo(unsigned int u) { return __uint_as_float(u << 16); }
__device__ __forceinline__ float bhi(unsigned int u) { return __uint_as_float(u & 0xFFFF0000u); }

// Fused: blocks [0,RB) = CSR rank histogram; blocks [RB,..) = layer-1 scores.
// (k_prep folded in: Wa/Wd recomputed per att-block into LDS — 2K FMA, trivial.)
__global__ __launch_bounds__(256) void k_ratt(
    const int* __restrict__ ei, int E, int EN,
    int* __restrict__ cnt, unsigned short* __restrict__ rank,
    const float* __restrict__ x, const float* __restrict__ W1,
    const float* __restrict__ as1, const float* __restrict__ ad1,
    float* __restrict__ asrc, float* __restrict__ adst, int N, int RB)
{
    if (blockIdx.x < RB) {
        int e = blockIdx.x * 256 + threadIdx.x;
        if (e >= EN) return;
        int dst = (e < E) ? ei[E + e] : (e - E);
        unsigned short r = (unsigned short)atomicAdd(&cnt[dst], 1);
        __builtin_nontemporal_store(r, rank + e);
        return;
    }
    __shared__ float s_wa[32], s_wd[32];
    int t = threadIdx.x;
    if (t < 32) {
        int k = t >> 2, hh = t & 3;
        float sa = 0.f, sd = 0.f;
        for (int cc = 0; cc < 32; cc++) {
            float w = W1[k * 128 + hh * 32 + cc];
            sa = fmaf(w, as1[hh * 32 + cc], sa);
            sd = fmaf(w, ad1[hh * 32 + cc], sd);
        }
        s_wa[t] = sa;   // index k*4+hh == t
        s_wd[t] = sd;
    }
    __syncthreads();
    int g = (blockIdx.x - RB) * 256 + t;
    int n = g >> 2;
    if (n >= N) return;
    int h = g & 3;
    const float* xr = x + (size_t)n * 8;
    float sa = 0.f, sd = 0.f;
    #pragma unroll
    for (int k = 0; k < 8; k++) {
        float xv = xr[k];
        sa = fmaf(xv, s_wa[k * 4 + h], sa);
        sd = fmaf(xv, s_wd[k * 4 + h], sd);
    }
    asrc[n * 4 + h] = sa;
    adst[n * 4 + h] = sd;
}

// Scan phase A: per-1024-tile sums.
__global__ __launch_bounds__(SCAN_B) void k_scanA(
    const int* __restrict__ cnt, int* __restrict__ bsum, int N)
{
    __shared__ int red[SCAN_B];
    int t = threadIdx.x;
    int i = blockIdx.x * SCAN_B + t;
    red[t] = (i < N) ? cnt[i] : 0;
    __syncthreads();
    #pragma unroll
    for (int off = SCAN_B / 2; off > 0; off >>= 1) {
        if (t < off) red[t] += red[t + off];
        __syncthreads();
    }
    if (t == 0) bsum[blockIdx.x] = red[0];
}

// Scan phase C with inlined phase B: each block reduces bsum[0..b) itself
// (G <= 1024), then intra-tile exclusive scan -> rowptr[N+1].
__global__ __launch_bounds__(SCAN_B) void k_scanC(
    const int* __restrict__ cnt, const int* __restrict__ bsum,
    int* __restrict__ rowptr, int N, int G)
{
    __shared__ int s[SCAN_B];
    int t = threadIdx.x, b = blockIdx.x;
    // block offset = sum of raw per-tile sums before this tile
    s[t] = (t < b && t < G) ? bsum[t] : 0;
    __syncthreads();
    #pragma unroll
    for (int off = SCAN_B / 2; off > 0; off >>= 1) {
        if (t < off) s[t] += s[t + off];
        __syncthreads();
    }
    int boff = s[0];
    __syncthreads();
    // intra-tile scan
    int i = b * SCAN_B + t;
    int v = (i < N) ? cnt[i] : 0;
    s[t] = v;
    __syncthreads();
    for (int off = 1; off < SCAN_B; off <<= 1) {
        int u = (t >= off) ? s[t - off] : 0;
        __syncthreads();
        s[t] += u;
        __syncthreads();
    }
    int excl = s[t] - v + boff;
    if (i < N) {
        rowptr[i] = excl;
        if (i == N - 1) rowptr[N] = excl + v;
    }
}

// Fused: blocks [0,PB) = atomic-free CSR placement; blocks [PB,PB+8) = pack W2.
__global__ __launch_bounds__(256) void k_plpk(
    const int* __restrict__ ei, int E, int EN,
    const int* __restrict__ rowptr, const unsigned short* __restrict__ rank,
    int* __restrict__ esrc,
    const float* __restrict__ W2, unsigned short* __restrict__ W2p, int PB)
{
    if (blockIdx.x < PB) {
        int e = blockIdx.x * 256 + threadIdx.x;
        if (e >= EN) return;
        int src, dst;
        if (e < E) { src = ei[e]; dst = ei[E + e]; }
        else       { src = dst = e - E; }
        esrc[rowptr[dst] + (int)rank[e]] = src;
        return;
    }
    int w = threadIdx.x >> 6, lane = threadIdx.x & 63;
    int quad = lane >> 4, lanelo = lane & 15;
    int tile_n = blockIdx.x - PB;               // 0..7
    size_t base = (((size_t)tile_n * 4 + w) * 64 + lane) * 8;
    #pragma unroll
    for (int j = 0; j < 8; j++) {
        int k = w * 32 + quad * 8 + j;
        int n = tile_n * 16 + lanelo;
        W2p[base + j] = f2b(W2[k * 128 + n]);
    }
}

// Layer-1 aggregation in INPUT space, 8-wide edge batch for gather MLP.
// 8 lanes/node: lane = head*2 + dim-half.
__global__ __launch_bounds__(256) void k_aggx(
    const int* __restrict__ rowptr, const int* __restrict__ esrc,
    const float* __restrict__ x, const float* __restrict__ asrc,
    const float* __restrict__ adst,
    float* __restrict__ y, float* __restrict__ denom, int N)
{
    int gid = blockIdx.x * 256 + threadIdx.x;
    int node = gid >> 3;
    if (node >= N) return;
    int l8 = threadIdx.x & 7;
    int h = l8 >> 1;
    int dh = (l8 & 1) << 2;
    float ad = adst[node * 4 + h];
    float a0 = 0.f, a1 = 0.f, a2 = 0.f, a3 = 0.f, d = 0.f;
    int j = rowptr[node], end = rowptr[node + 1];
    for (; j + 8 <= end; j += 8) {
        int s[8];
        #pragma unroll
        for (int i = 0; i < 8; i++) s[i] = esrc[j + i];
        float A[8];
        #pragma unroll
        for (int i = 0; i < 8; i++) A[i] = asrc[s[i] * 4 + h];
        float4 xv[8];
        #pragma unroll
        for (int i = 0; i < 8; i++)
            xv[i] = *reinterpret_cast<const float4*>(x + (size_t)s[i] * 8 + dh);
        #pragma unroll
        for (int i = 0; i < 8; i++) {
            float a = A[i] + ad;
            a = a > 0.f ? a : NEG_SLOPE * a;
            float w = __expf(a);
            a0 = fmaf(w, xv[i].x, a0); a1 = fmaf(w, xv[i].y, a1);
            a2 = fmaf(w, xv[i].z, a2); a3 = fmaf(w, xv[i].w, a3); d += w;
        }
    }
    if (j + 4 <= end) {
        int s[4];
        #pragma unroll
        for (int i = 0; i < 4; i++) s[i] = esrc[j + i];
        float A[4];
        #pragma unroll
        for (int i = 0; i < 4; i++) A[i] = asrc[s[i] * 4 + h];
        float4 xv[4];
        #pragma unroll
        for (int i = 0; i < 4; i++)
            xv[i] = *reinterpret_cast<const float4*>(x + (size_t)s[i] * 8 + dh);
        #pragma unroll
        for (int i = 0; i < 4; i++) {
            float a = A[i] + ad;
            a = a > 0.f ? a : NEG_SLOPE * a;
            float w = __expf(a);
            a0 = fmaf(w, xv[i].x, a0); a1 = fmaf(w, xv[i].y, a1);
            a2 = fmaf(w, xv[i].z, a2); a3 = fmaf(w, xv[i].w, a3); d += w;
        }
        j += 4;
    }
    for (; j < end; j++) {
        int src = esrc[j];
        float a = asrc[src * 4 + h] + ad;
        a = a > 0.f ? a : NEG_SLOPE * a;
        float w = __expf(a);
        float4 xv = *reinterpret_cast<const float4*>(x + (size_t)src * 8 + dh);
        a0 = fmaf(w, xv.x, a0); a1 = fmaf(w, xv.y, a1);
        a2 = fmaf(w, xv.z, a2); a3 = fmaf(w, xv.w, a3); d += w;
    }
    float4 o = {a0, a1, a2, a3};
    *reinterpret_cast<float4*>(y + ((size_t)node * 4 + h) * 8 + dh) = o;
    if (dh == 0) denom[node * 4 + h] = d;
}

// Layer-2 feature transform with FUSED out1 computation (no out1b round-trip):
// stage 1: out1 tile (32 nodes x 128ch) = relu(y@W1/denom + b1) -> bf16 in LDS
//          (XOR-swizzled: byte ^= (row&7)<<4, keeps A-frag ds_read_b128 2-way).
// stage 2: h2 = out1 @ W2 via MFMA + fused layer-2 score computation.
__global__ __launch_bounds__(256) void k_feat2(
    const float* __restrict__ y, const float* __restrict__ denom,
    const float* __restrict__ W1, const float* __restrict__ bias1,
    const unsigned short* __restrict__ W2p,
    const float* __restrict__ att_src, const float* __restrict__ att_dst,
    unsigned short* __restrict__ h, float* __restrict__ asrc,
    float* __restrict__ adst, int N)
{
    __shared__ uint4 s_tile[512];               // 32 nodes x 256B
    char* s_a = reinterpret_cast<char*>(s_tile);
    int t = threadIdx.x;
    int mbase = blockIdx.x * 32;

    // ---- stage 1: out1 tile into LDS ----
    {
        int nl = t >> 3;                        // 0..31
        int seg = t & 7;                        // 16 channels each
        int node = mbase + nl;
        if (node >= N) node = N - 1;            // clamp; stores guarded later
        int head = seg >> 1;
        const float* yr = y + ((size_t)node * 4 + head) * 8;
        float inv = 1.f / denom[node * 4 + head];
        float y8[8];
        #pragma unroll
        for (int k = 0; k < 8; k++) y8[k] = yr[k];
        int c0 = seg * 16;
        float acc16[16];
        #pragma unroll
        for (int c = 0; c < 16; c++) acc16[c] = 0.f;
        #pragma unroll
        for (int k = 0; k < 8; k++) {
            float yk = y8[k];
            const float4* wr = reinterpret_cast<const float4*>(W1 + k * 128 + c0);
            #pragma unroll
            for (int q = 0; q < 4; q++) {
                float4 wv = wr[q];
                acc16[q * 4 + 0] = fmaf(yk, wv.x, acc16[q * 4 + 0]);
                acc16[q * 4 + 1] = fmaf(yk, wv.y, acc16[q * 4 + 1]);
                acc16[q * 4 + 2] = fmaf(yk, wv.z, acc16[q * 4 + 2]);
                acc16[q * 4 + 3] = fmaf(yk, wv.w, acc16[q * 4 + 3]);
            }
        }
        unsigned int dw[8];
        #pragma unroll
        for (int c = 0; c < 8; c++) {
            float v0 = acc16[2 * c]     * inv + bias1[c0 + 2 * c];
            float v1 = acc16[2 * c + 1] * inv + bias1[c0 + 2 * c + 1];
            v0 = v0 > 0.f ? v0 : 0.f;
            v1 = v1 > 0.f ? v1 : 0.f;
            dw[c] = ((unsigned int)f2b(v1) << 16) | f2b(v0);
        }
        int byte0 = nl * 256 + seg * 32;
        int swz = (nl & 7) << 4;
        *reinterpret_cast<uint4*>(&s_a[byte0 ^ swz]) =
            make_uint4(dw[0], dw[1], dw[2], dw[3]);
        *reinterpret_cast<uint4*>(&s_a[(byte0 + 16) ^ swz]) =
            make_uint4(dw[4], dw[5], dw[6], dw[7]);
    }
    __syncthreads();

    // ---- stage 2: MFMA, A from LDS ----
    int w = t >> 6;
    int lane = t & 63;
    int quad = lane >> 4, lanelo = lane & 15;
    int wcb = w * 32;                           // wave col base == head w * 32

    f32x4 acc[2][2];
    #pragma unroll
    for (int rt = 0; rt < 2; rt++)
        #pragma unroll
        for (int ct = 0; ct < 2; ct++)
            acc[rt][ct] = (f32x4){0.f, 0.f, 0.f, 0.f};

    #pragma unroll
    for (int kc = 0; kc < 4; kc++) {
        bf16x8 a[2], b[2];
        #pragma unroll
        for (int rt = 0; rt < 2; rt++) {
            int nl = rt * 16 + lanelo;
            int byte = nl * 256 + kc * 64 + quad * 16;
            a[rt] = *reinterpret_cast<const bf16x8*>(&s_a[byte ^ ((nl & 7) << 4)]);
        }
        #pragma unroll
        for (int ct = 0; ct < 2; ct++) {
            int tile_n = w * 2 + ct;
            b[ct] = *reinterpret_cast<const bf16x8*>(
                W2p + (((size_t)tile_n * 4 + kc) * 64 + lane) * 8);
        }
        #pragma unroll
        for (int rt = 0; rt < 2; rt++)
            #pragma unroll
            for (int ct = 0; ct < 2; ct++)
                acc[rt][ct] = __builtin_amdgcn_mfma_f32_16x16x32_bf16(
                    a[rt], b[ct], acc[rt][ct], 0, 0, 0);
    }

    // Epilogue. C/D layout: n = lane&15, m = quad*4 + reg.
    float as_[2], ad_[2];
    #pragma unroll
    for (int ct = 0; ct < 2; ct++) {
        int col = wcb + ct * 16 + lanelo;
        as_[ct] = att_src[col];
        ad_[ct] = att_dst[col];
    }
    #pragma unroll
    for (int rt = 0; rt < 2; rt++) {
        #pragma unroll
        for (int reg = 0; reg < 4; reg++) {
            int node = mbase + rt * 16 + quad * 4 + reg;
            bool ok = node < N;
            float v0 = acc[rt][0][reg], v1 = acc[rt][1][reg];
            if (ok) {
                h[(size_t)node * 128 + wcb + lanelo]      = f2b(v0);
                h[(size_t)node * 128 + wcb + 16 + lanelo] = f2b(v1);
            }
            float ps = v0 * as_[0] + v1 * as_[1];
            float pd = v0 * ad_[0] + v1 * ad_[1];
            #pragma unroll
            for (int off = 8; off >= 1; off >>= 1) {
                ps += __shfl_xor(ps, off, 64);
                pd += __shfl_xor(pd, off, 64);
            }
            if (ok && lanelo == 0) {
                asrc[node * 4 + w] = ps;
                adst[node * 4 + w] = pd;
            }
        }
    }
}

// Layer-2 aggregation core: 16 lanes/node, 8 ch/lane, 8-wide edge batch
// (doubles outstanding gathers per wave — kernel is gather-latency-bound).
__device__ __forceinline__ void agg_edge(float w, uint4 u, float acc[8])
{
    acc[0] = fmaf(w, blo(u.x), acc[0]); acc[1] = fmaf(w, bhi(u.x), acc[1]);
    acc[2] = fmaf(w, blo(u.y), acc[2]); acc[3] = fmaf(w, bhi(u.y), acc[3]);
    acc[4] = fmaf(w, blo(u.z), acc[4]); acc[5] = fmaf(w, bhi(u.z), acc[5]);
    acc[6] = fmaf(w, blo(u.w), acc[6]); acc[7] = fmaf(w, bhi(u.w), acc[7]);
}

__device__ __forceinline__ void agg_core16(
    int n, int l4,
    const int* __restrict__ rowptr, const int* __restrict__ esrc,
    const uint4* __restrict__ h /* 16 uint4 per node */,
    const float* __restrict__ asrc, const float* __restrict__ adst,
    float acc[8], float& d)
{
    int head = l4 >> 2;
    float ad = adst[n * 4 + head];
    #pragma unroll
    for (int k = 0; k < 8; k++) acc[k] = 0.f;
    d = 0.f;
    int j = rowptr[n], end = rowptr[n + 1];

    for (; j + 8 <= end; j += 8) {
        int s[8];
        #pragma unroll
        for (int i = 0; i < 8; i++) s[i] = esrc[j + i];
        float A[8];
        #pragma unroll
        for (int i = 0; i < 8; i++) A[i] = asrc[s[i] * 4 + head];
        uint4 u[8];
        #pragma unroll
        for (int i = 0; i < 8; i++) u[i] = h[(size_t)s[i] * 16 + l4];
        #pragma unroll
        for (int i = 0; i < 8; i++) {
            float a = A[i] + ad;
            a = a > 0.f ? a : NEG_SLOPE * a;
            float w = __expf(a);
            agg_edge(w, u[i], acc); d += w;
        }
    }
    if (j + 4 <= end) {
        int s[4];
        #pragma unroll
        for (int i = 0; i < 4; i++) s[i] = esrc[j + i];
        float A[4];
        #pragma unroll
        for (int i = 0; i < 4; i++) A[i] = asrc[s[i] * 4 + head];
        uint4 u[4];
        #pragma unroll
        for (int i = 0; i < 4; i++) u[i] = h[(size_t)s[i] * 16 + l4];
        #pragma unroll
        for (int i = 0; i < 4; i++) {
            float a = A[i] + ad;
            a = a > 0.f ? a : NEG_SLOPE * a;
            float w = __expf(a);
            agg_edge(w, u[i], acc); d += w;
        }
        j += 4;
    }
    for (; j < end; j++) {
        int src = esrc[j];
        float a = asrc[src * 4 + head] + ad;
        a = a > 0.f ? a : NEG_SLOPE * a;
        float w = __expf(a);
        uint4 u = h[(size_t)src * 16 + l4];
        agg_edge(w, u, acc); d += w;
    }
}

// Layer-2 aggregate + fused final: mean over heads, +bias2, relu, dot W_lin.
__global__ __launch_bounds__(256) void k_agg2(
    const int* __restrict__ rowptr, const int* __restrict__ esrc,
    const uint4* __restrict__ h, const float* __restrict__ asrc,
    const float* __restrict__ adst, const float* __restrict__ bias2,
    const float* __restrict__ Wlin, const float* __restrict__ blin,
    float* __restrict__ out, int N)
{
    int gid = blockIdx.x * 256 + threadIdx.x;
    int node = gid >> 4;
    if (node >= N) return;
    int l4 = threadIdx.x & 15;
    float acc[8], d;
    agg_core16(node, l4, rowptr, esrc, h, asrc, adst, acc, d);
    float inv = 1.f / d;
    float v[8];
    #pragma unroll
    for (int k = 0; k < 8; k++) v[k] = acc[k] * inv;
    // head-mean: lanes differing in bits 2-3 of l4 hold same cc-octet, other heads
    #pragma unroll
    for (int k = 0; k < 8; k++) {
        v[k] += __shfl_xor(v[k], 4, 64);
        v[k] += __shfl_xor(v[k], 8, 64);
    }
    int cc = (l4 & 3) * 8;
    const float4 b0 = *reinterpret_cast<const float4*>(bias2 + cc);
    const float4 b1 = *reinterpret_cast<const float4*>(bias2 + cc + 4);
    const float4 w0 = *reinterpret_cast<const float4*>(Wlin + cc);
    const float4 w1 = *reinterpret_cast<const float4*>(Wlin + cc + 4);
    float bb[8] = {b0.x, b0.y, b0.z, b0.w, b1.x, b1.y, b1.z, b1.w};
    float ww[8] = {w0.x, w0.y, w0.z, w0.w, w1.x, w1.y, w1.z, w1.w};
    float t = 0.f;
    #pragma unroll
    for (int k = 0; k < 8; k++) {
        float m = 0.25f * v[k] + bb[k];
        float y = m > 0.f ? m : 0.f;
        t = fmaf(y, ww[k], t);
    }
    t += __shfl_xor(t, 1, 64);
    t += __shfl_xor(t, 2, 64);
    if (l4 == 0) out[node] = t + blin[0];
}

extern "C" void kernel_launch(void* const* d_in, const int* in_sizes, int n_in,
                              void* d_out, int out_size, void* d_ws, size_t ws_size,
                              hipStream_t stream)
{
    const float* x   = (const float*)d_in[0];
    const int*   ei  = (const int*)  d_in[1];
    const float* W1  = (const float*)d_in[2];
    const float* as1 = (const float*)d_in[3];
    const float* ad1 = (const float*)d_in[4];
    const float* b1  = (const float*)d_in[5];
    const float* W2  = (const float*)d_in[6];
    const float* as2 = (const float*)d_in[7];
    const float* ad2 = (const float*)d_in[8];
    const float* b2  = (const float*)d_in[9];
    const float* Wl  = (const float*)d_in[10];
    const float* bl  = (const float*)d_in[11];
    float* out = (float*)d_out;

    int N  = in_sizes[0] / 8;
    int E  = in_sizes[1] / 2;
    int EN = E + N;
    int G  = (N + SCAN_B - 1) / SCAN_B;

    float* ws    = (float*)d_ws;
    unsigned short* A = (unsigned short*)ws;    // N*128 bf16: h2
    float* B     = ws + (size_t)N * 64;         // region: rank, then y
    float* y     = B;                           // N*32 fp32 (layer-1 aggregate)
    unsigned short* rank = (unsigned short*)B;  // EN u16, dead before k_aggx
    float* asrc  = B + (size_t)N * 128;         // N*4
    float* adst  = asrc + (size_t)N * 4;        // N*4
    int* cnt     = (int*)(adst + (size_t)N * 4);// N
    int* rowptr  = cnt + N;                     // N+1
    int* bsum    = rowptr + N + 1;              // G
    int* esrc    = bsum + G;                    // EN
    unsigned short* W2p = (unsigned short*)(esrc + EN);  // 16384 bf16
    float* denom = (float*)(W2p + 16384);       // N*4

    int eb = (EN + 255) / 256;
    int ab = (N + 63) / 64;                     // att1 blocks (4 lanes/node)
    int nb = (N + 15) / 16;                     // agg2: 16 nodes/block

    hipMemsetAsync(cnt, 0, (size_t)N * sizeof(int), stream);
    // rank + layer-1 scores (+ folded W1/att prep) in one launch
    k_ratt<<<eb + ab, 256, 0, stream>>>(ei, E, EN, cnt, rank,
                                        x, W1, as1, ad1, asrc, adst, N, eb);
    k_scanA<<<G, SCAN_B, 0, stream>>>(cnt, bsum, N);
    k_scanC<<<G, SCAN_B, 0, stream>>>(cnt, bsum, rowptr, N, G);
    // placement + W2 packing in one launch
    k_plpk<<<eb + 8, 256, 0, stream>>>(ei, E, EN, rowptr, rank, esrc, W2, W2p, eb);

    // Layer 1 (input-space aggregation: no h1 materialization)
    k_aggx<<<(N + 31) / 32, 256, 0, stream>>>(rowptr, esrc, x, asrc, adst,
                                              y, denom, N);

    // Layer 2: fused out1 + matmul + scores, then aggregation
    k_feat2<<<(N + 31) / 32, 256, 0, stream>>>(y, denom, W1, b1, W2p,
                                               as2, ad2, A, asrc, adst, N);
    k_agg2<<<nb, 256, 0, stream>>>(rowptr, esrc, (const uint4*)A,
                                   asrc, adst, b2, Wl, bl, out, N);
}